// Round 14
// baseline (156.452 us; speedup 1.0000x reference)
//
#include <hip/hip_runtime.h>
#include <hip/hip_fp16.h>
#include <math.h>

#define HH 512
#define WW 512
#define BB 32
#define CHUNK 16

typedef unsigned u32;

#define NEG_INF2 0xFC00FC00u
#define POS_INF2 0x7C007C00u

// Packed f16 ops via inline asm (ROCm 7.2 headers lack __hmin2/__hmax2).
__device__ __forceinline__ u32 pkmin(u32 a, u32 b) {
    u32 r; asm("v_pk_min_f16 %0, %1, %2" : "=v"(r) : "v"(a), "v"(b)); return r;
}
__device__ __forceinline__ u32 pkmax(u32 a, u32 b) {
    u32 r; asm("v_pk_max_f16 %0, %1, %2" : "=v"(r) : "v"(a), "v"(b)); return r;
}
__device__ __forceinline__ u32 pksub(u32 a, u32 b) {   // a - b, both halves
    u32 r; asm("v_pk_add_f16 %0, %1, %2 neg_lo:[0,1] neg_hi:[0,1]" : "=v"(r) : "v"(a), "v"(b)); return r;
}
__device__ __forceinline__ u32 min3p(u32 a, u32 b, u32 c) { return pkmin(pkmin(a, b), c); }
__device__ __forceinline__ u32 max3p(u32 a, u32 b, u32 c) { return pkmax(pkmax(a, b), c); }

// {lo: a.hi, hi: b.lo} — the shift-by-one-element view between packed pairs.
__device__ __forceinline__ u32 shl1(u32 a, u32 b) {
    return __builtin_amdgcn_alignbit(b, a, 16);
}

union H2U { __half2 h; u32 u; };
__device__ __forceinline__ u32 f2toh2(float lo, float hi) {
    H2U t; t.h = __float22half2_rn(make_float2(lo, hi)); return t.u;
}
__device__ __forceinline__ float2 h2tof2(u32 v) {
    H2U t; t.u = v; return __half22float2(t.h);
}

// Clamped 12-element row load as 6 packed pairs (element e_i = col gx0-4+i).
// Row clamp wave-uniform; col bases pre-clamped. Edge fixups (duplicate an
// in-window value; never changes a min): e3=e0 (lane s==0), e8=e7 (s==127).
template <int F32>
__device__ __forceinline__ void loadrow6(const float* __restrict__ imgF,
                                         const unsigned short* __restrict__ imgH,
                                         int R, int cm4, int c0, int cp4,
                                         bool isL, bool isR, u32* X) {
    const int Rc = R < 0 ? 0 : (R > HH - 1 ? HH - 1 : R);
    if (F32) {
        const float* rb = imgF + (size_t)Rc * WW;
        float4 v0 = *(const float4*)(rb + cm4);
        float4 v1 = *(const float4*)(rb + c0);
        float4 v2 = *(const float4*)(rb + cp4);
        X[0] = f2toh2(v0.x, v0.y); X[1] = f2toh2(v0.z, v0.w);
        X[2] = f2toh2(v1.x, v1.y); X[3] = f2toh2(v1.z, v1.w);
        X[4] = f2toh2(v2.x, v2.y); X[5] = f2toh2(v2.z, v2.w);
    } else {
        const unsigned short* rb = imgH + (size_t)Rc * WW;
        uint2 a = *(const uint2*)(rb + cm4);
        uint2 b = *(const uint2*)(rb + c0);
        uint2 c = *(const uint2*)(rb + cp4);
        X[0] = a.x; X[1] = a.y; X[2] = b.x; X[3] = b.y; X[4] = c.x; X[5] = c.y;
    }
    u32 fl = __builtin_amdgcn_perm(X[0], X[1], 0x05040100u);   // {X1.lo, X0.lo}
    X[1] = isL ? fl : X[1];
    u32 fr = __builtin_amdgcn_perm(X[4], X[3], 0x07060302u);   // {X4.hi, X3.hi}
    X[4] = isR ? fr : X[4];
}

// One row of the T=2 packed-f16 pipeline. Ring roles passed explicitly
// (4-row caller body -> zero cross-iteration copies). Masks mk[8]:
// mn0 {0..3} (pkmin), x1 {4,5} (pkmax), mn1 {6,7} (pkmin).
template <int SRCF32, int FUSED>
__device__ __forceinline__ void rowstep(
    const float* __restrict__ imgF, const unsigned short* __restrict__ imgH,
    const float* __restrict__ cmp, unsigned short* __restrict__ outp,
    float& acc0, float& acc1,
    int R, int cm4, int gx0, int cp4, bool isL, bool isR, bool doStore,
    u32 (&X)[6], u32 (&XL)[6],
    u32 (&hm0o)[6], u32 (&hm0n)[6], u32 (&mn0p)[4],
    u32 (&hx0o)[4], u32 (&hx0n)[4],
    u32 (&x0o)[4], u32 (&x0n)[4],
    u32 (&hm1o)[4], u32 (&hm1n)[4], u32 (&mn1p)[2],
    u32 (&hx1o)[2], u32 (&hx1n)[2],
    u32 (&x1o)[2], u32 (&x1n)[2],
    const u32 (&mk)[8],
    float4& cqC, float4& cqL) {
    loadrow6<SRCF32>(imgF, imgH, R + 3, cm4, gx0, cp4, isL, isR, XL);

    float4 cmpCur;
    if (FUSED) {
        cmpCur = cqC;
        int Rc = R - 1;
        Rc = Rc < 0 ? 0 : (Rc > HH - 1 ? HH - 1 : Rc);
        cqL = *(const float4*)(cmp + (size_t)Rc * WW + gx0);
    }

    // ---- iter1 horizontal min3, row R (pairs 0..5; e0/e11 garbage, unconsumed)
    u32 L[7];
    L[0] = shl1(X[0], X[0]);
    #pragma unroll
    for (int j = 1; j <= 5; ++j) L[j] = shl1(X[j - 1], X[j]);
    L[6] = shl1(X[5], X[5]);
    u32 hm0c[6];
    #pragma unroll
    for (int j = 0; j < 6; ++j) hm0c[j] = min3p(L[j], X[j], L[j + 1]);

    // ---- iter1 min-pool row R-1 (vertical) + masks
    u32 M[6];
    #pragma unroll
    for (int j = 0; j < 6; ++j) M[j] = min3p(hm0o[j], hm0n[j], hm0c[j]);
    if (!((unsigned)(R - 1) < HH)) {            // wave-uniform, rarely taken
        #pragma unroll
        for (int j = 0; j < 6; ++j) M[j] = NEG_INF2;
    }
    M[0] = pkmin(M[0], mk[0]); M[1] = pkmin(M[1], mk[1]);
    M[4] = pkmin(M[4], mk[2]); M[5] = pkmin(M[5], mk[3]);

    // ---- horiz max3 of M, pairs 1..4
    u32 ML[6];
    #pragma unroll
    for (int j = 1; j <= 5; ++j) ML[j] = shl1(M[j - 1], M[j]);
    u32 hx0c[4];
    #pragma unroll
    for (int j = 0; j < 4; ++j) hx0c[j] = max3p(ML[j + 1], M[j + 1], ML[j + 2]);

    // ---- iter1 update: x1 row R-2 (pairs 1..4 -> idx 0..3 = e2..e9)
    u32 x1c[4];
    #pragma unroll
    for (int j = 0; j < 4; ++j) {
        u32 mp = max3p(hx0o[j], hx0n[j], hx0c[j]);
        u32 ct = pkmax(pksub(mp, mn0p[j]), 0u);
        x1c[j] = pkmax(pksub(x0o[j], ct), 0u);
    }
    if (!((unsigned)(R - 2) < HH)) {
        #pragma unroll
        for (int j = 0; j < 4; ++j) x1c[j] = POS_INF2;
    }
    x1c[0] = pkmax(x1c[0], mk[4]);
    x1c[3] = pkmax(x1c[3], mk[5]);

    // rotate iter1 rings (renamed by unrolled caller)
    #pragma unroll
    for (int j = 0; j < 6; ++j) hm0o[j] = hm0c[j];
    #pragma unroll
    for (int j = 0; j < 4; ++j) { mn0p[j] = M[j + 1]; hx0o[j] = hx0c[j]; x0o[j] = X[j + 1]; }

    // ---- iter2 horizontal min3 of x1 (idx 0..3 = e2..e9)
    u32 XL1[5];
    XL1[0] = shl1(x1c[0], x1c[0]);
    #pragma unroll
    for (int j = 1; j <= 3; ++j) XL1[j] = shl1(x1c[j - 1], x1c[j]);
    XL1[4] = shl1(x1c[3], x1c[3]);
    u32 hm1c[4];
    #pragma unroll
    for (int j = 0; j < 4; ++j) hm1c[j] = min3p(XL1[j], x1c[j], XL1[j + 1]);

    // ---- iter2 min-pool row R-3 + masks
    u32 M1[4];
    #pragma unroll
    for (int j = 0; j < 4; ++j) M1[j] = min3p(hm1o[j], hm1n[j], hm1c[j]);
    if (!((unsigned)(R - 3) < HH)) {
        #pragma unroll
        for (int j = 0; j < 4; ++j) M1[j] = NEG_INF2;
    }
    M1[0] = pkmin(M1[0], mk[6]);
    M1[3] = pkmin(M1[3], mk[7]);

    // ---- horiz max3 of M1 at output pairs (idx 1,2 = e4..e7)
    u32 M1s[4];
    #pragma unroll
    for (int j = 1; j <= 3; ++j) M1s[j] = shl1(M1[j - 1], M1[j]);
    u32 hx1c[2];
    hx1c[0] = max3p(M1s[1], M1[1], M1s[2]);
    hx1c[1] = max3p(M1s[2], M1[2], M1s[3]);

    // ---- iter2 update: out row R-4 (wave-uniform branch)
    if (doStore) {
        u32 o[2];
        #pragma unroll
        for (int k = 0; k < 2; ++k) {
            u32 mp = max3p(hx1o[k], hx1n[k], hx1c[k]);
            u32 ct = pkmax(pksub(mp, mn1p[k]), 0u);
            o[k] = pkmax(pksub(x1o[k], ct), 0u);
        }
        if (FUSED) {
            float2 f0 = h2tof2(o[0]);
            float2 f1 = h2tof2(o[1]);
            acc0 += f0.x * cmpCur.x + f0.y * cmpCur.y + f1.x * cmpCur.z + f1.y * cmpCur.w;
            acc1 += f0.x + f0.y + f1.x + f1.y;
        } else {
            uint2 ov;
            ov.x = o[0]; ov.y = o[1];
            *(uint2*)(outp + (size_t)(R - 4) * WW + gx0) = ov;
        }
    }

    // rotate iter2 rings
    #pragma unroll
    for (int j = 0; j < 4; ++j) hm1o[j] = hm1c[j];
    mn1p[0] = M1[1]; mn1p[1] = M1[2];
    hx1o[0] = hx1c[0]; hx1o[1] = hx1c[1];
    x1o[0] = x1c[1]; x1o[1] = x1c[2];
}

// Two fused soft-skeletonize iterations (T=2), packed-f16 via v_pk_min/max
// inline asm, f16 intermediates, no LDS, 4-row rotated loop body
// (I$-resident, zero cross-iteration movs). Packing halves VALU ops/row
// (~216 -> ~130) and ring state (target <=128 VGPR -> 4 waves/SIMD).
template <int SRCF32, int FUSED>
__global__ __launch_bounds__(256) void skel2h_t(const float* __restrict__ sfA,
                                                const float* __restrict__ sfB,
                                                const unsigned short* __restrict__ shA,
                                                const unsigned short* __restrict__ shB,
                                                const float* __restrict__ cmpA,
                                                const float* __restrict__ cmpB,
                                                unsigned short* __restrict__ dst,
                                                float* __restrict__ partials) {
    const int s = blockIdx.x * 64 + threadIdx.x;            // span 0..127
    const int y0 = (blockIdx.y * 4 + threadIdx.y) * CHUNK;  // output row start
    const int z = blockIdx.z;
    const float* imgF = nullptr;
    const unsigned short* imgH = nullptr;
    if (SRCF32) imgF = (z < BB) ? (sfA + (size_t)z * (HH * WW))
                                : (sfB + (size_t)(z - BB) * (HH * WW));
    else        imgH = (z < BB) ? (shA + (size_t)z * (HH * WW))
                                : (shB + (size_t)(z - BB) * (HH * WW));
    const float* cmp = nullptr;
    if (FUSED) cmp = (z < BB) ? (cmpA + (size_t)z * (HH * WW))
                              : (cmpB + (size_t)(z - BB) * (HH * WW));
    unsigned short* outp = FUSED ? nullptr : (dst + (size_t)z * (HH * WW));
    const int gx0 = 4 * s;
    const bool isL = (s == 0), isR = (s == 127);
    const int cm4 = isL ? 0 : gx0 - 4;
    const int cp4 = isR ? gx0 : gx0 + 4;

    // per-lane boundary mask words (lo16 = even element, hi16 = odd)
    u32 mk[8];
    mk[0] = isL ? 0xFC007C00u : POS_INF2;   // mn0 pair0: force e1 -> -inf
    mk[1] = isL ? NEG_INF2    : POS_INF2;   // mn0 pair1: force e2,e3
    mk[2] = isR ? NEG_INF2    : POS_INF2;   // mn0 pair4: force e8,e9
    mk[3] = isR ? 0x7C00FC00u : POS_INF2;   // mn0 pair5: force e10
    mk[4] = isL ? POS_INF2    : NEG_INF2;   // x1 idx0: force e2,e3 -> +inf
    mk[5] = isR ? POS_INF2    : NEG_INF2;   // x1 idx3: force e8,e9
    mk[6] = isL ? 0xFC007C00u : POS_INF2;   // mn1 idx0: force e3
    mk[7] = isR ? 0x7C00FC00u : POS_INF2;   // mn1 idx3: force e8

    // ring state (packed pairs)
    u32 hm0a[6], hm0b[6], mn0p[4];
    u32 hx0a[4], hx0b[4], x0a[4], x0b[4];
    u32 hm1a[4], hm1b[4], mn1p[2];
    u32 hx1a[2], hx1b[2], x1a[2], x1b[2];
    u32 xs0[6], xs1[6], xs2[6], xs3[6];
    float4 cq0, cq1, cq2, cq3;

    #pragma unroll
    for (int j = 0; j < 6; ++j) { hm0a[j] = POS_INF2; hm0b[j] = POS_INF2; }
    #pragma unroll
    for (int j = 0; j < 4; ++j) {
        mn0p[j] = NEG_INF2; hx0a[j] = NEG_INF2; hx0b[j] = NEG_INF2;
        x0a[j] = POS_INF2; x0b[j] = POS_INF2;
        hm1a[j] = POS_INF2; hm1b[j] = POS_INF2;
    }
    #pragma unroll
    for (int k = 0; k < 2; ++k) {
        mn1p[k] = NEG_INF2; hx1a[k] = NEG_INF2; hx1b[k] = NEG_INF2;
        x1a[k] = POS_INF2; x1b[k] = POS_INF2;
    }
    cq0.x = cq0.y = cq0.z = cq0.w = 0.f;
    cq1 = cq0; cq2 = cq0; cq3 = cq0;

    float acc0 = 0.0f, acc1 = 0.0f;

    loadrow6<SRCF32>(imgF, imgH, y0 - 4, cm4, gx0, cp4, isL, isR, xs0);
    loadrow6<SRCF32>(imgF, imgH, y0 - 3, cm4, gx0, cp4, isL, isR, xs1);
    loadrow6<SRCF32>(imgF, imgH, y0 - 2, cm4, gx0, cp4, isL, isR, xs2);

    #pragma unroll 1
    for (int it = 0; it < (CHUNK + 8) / 4; ++it) {
        const int Rb = y0 - 4 + 4 * it;
        const bool doStore = (it >= 2);
        rowstep<SRCF32, FUSED>(imgF, imgH, cmp, outp, acc0, acc1,
            Rb + 0, cm4, gx0, cp4, isL, isR, doStore,
            xs0, xs3, hm0a, hm0b, mn0p, hx0a, hx0b, x0a, x0b,
            hm1a, hm1b, mn1p, hx1a, hx1b, x1a, x1b, mk, cq0, cq3);
        rowstep<SRCF32, FUSED>(imgF, imgH, cmp, outp, acc0, acc1,
            Rb + 1, cm4, gx0, cp4, isL, isR, doStore,
            xs1, xs0, hm0b, hm0a, mn0p, hx0b, hx0a, x0b, x0a,
            hm1b, hm1a, mn1p, hx1b, hx1a, x1b, x1a, mk, cq1, cq0);
        rowstep<SRCF32, FUSED>(imgF, imgH, cmp, outp, acc0, acc1,
            Rb + 2, cm4, gx0, cp4, isL, isR, doStore,
            xs2, xs1, hm0a, hm0b, mn0p, hx0a, hx0b, x0a, x0b,
            hm1a, hm1b, mn1p, hx1a, hx1b, x1a, x1b, mk, cq2, cq1);
        rowstep<SRCF32, FUSED>(imgF, imgH, cmp, outp, acc0, acc1,
            Rb + 3, cm4, gx0, cp4, isL, isR, doStore,
            xs3, xs2, hm0b, hm0a, mn0p, hx0b, hx0a, x0b, x0a,
            hm1b, hm1a, mn1p, hx1b, hx1a, x1b, x1a, mk, cq3, cq2);
    }

    if (FUSED) {
        for (int off = 32; off; off >>= 1) {
            acc0 += __shfl_down(acc0, off);
            acc1 += __shfl_down(acc1, off);
        }
        __shared__ float red[4][2];
        if (threadIdx.x == 0) { red[threadIdx.y][0] = acc0; red[threadIdx.y][1] = acc1; }
        __syncthreads();
        if (threadIdx.x == 0 && threadIdx.y == 0) {
            const int tile = blockIdx.x * gridDim.y + blockIdx.y;  // 0..15
            float* p = partials + ((size_t)z * 16 + tile) * 2;
            p[0] = red[0][0] + red[1][0] + red[2][0] + red[3][0];
            p[1] = red[0][1] + red[1][1] + red[2][1] + red[3][1];
        }
    }
}

// partials layout: [z][16 tile slots][2] (first ntiles used per z);
// z<32: (sum clp*tgt, sum clp); z>=32: (sum skt*prd, sum skt)
__global__ __launch_bounds__(64) void finalize2(const float* __restrict__ partials,
                                                int ntiles,
                                                float* __restrict__ out) {
    const int b = threadIdx.x;
    float iflat = 0.f, tflat = 0.f;
    if (b < BB) {
        float v0 = 0.f, v1 = 0.f, v2 = 0.f, v3 = 0.f;
        for (int t = 0; t < ntiles; ++t) {
            v0 += partials[((size_t)b * 16 + t) * 2 + 0];
            v1 += partials[((size_t)b * 16 + t) * 2 + 1];
            v2 += partials[((size_t)(b + BB) * 16 + t) * 2 + 0];
            v3 += partials[((size_t)(b + BB) * 16 + t) * 2 + 1];
        }
        iflat = (v0 + 1e-6f) / (v1 + 1e-6f);
        tflat = (v2 + 1e-6f) / (v3 + 1e-6f);
    }
    float prod = iflat * tflat;
    float ssum = iflat + tflat;
    for (int off = 32; off; off >>= 1) {
        prod += __shfl_down(prod, off);
        ssum += __shfl_down(ssum, off);
    }
    if (threadIdx.x == 0) out[0] = 1.0f - 2.0f * prod / ssum;
}

extern "C" void kernel_launch(void* const* d_in, const int* in_sizes, int n_in,
                              void* d_out, int out_size, void* d_ws, size_t ws_size,
                              hipStream_t stream) {
    const float* pred = (const float*)d_in[0];
    const float* target = (const float*)d_in[1];
    float* out = (float*)d_out;
    char* ws = (char*)d_ws;
    const size_t N = (size_t)HH * WW;
    const size_t HALF = (size_t)BB * N;                 // elements per 32-image half
    const size_t IMG16 = HALF * sizeof(unsigned short); // 16 MB (f16, 32 imgs)

    dim3 block(64, 4);
    const int nby = HH / (CHUNK * 4);                   // 8
    const int ntiles = 2 * nby;                         // 16

    if (ws_size >= 4 * IMG16 + (1 << 16)) {
        // z=64 path: both chains per dispatch; f16 ping-pong A<->B (32MB each)
        unsigned short* A = (unsigned short*)ws;
        unsigned short* B = (unsigned short*)(ws + 2 * IMG16);
        float* partials = (float*)(ws + 4 * IMG16);     // 64*16*2 floats
        dim3 grid(2, nby, 2 * BB);
        skel2h_t<1, 0><<<grid, block, 0, stream>>>(pred, target, nullptr, nullptr,
                                                   nullptr, nullptr, A, nullptr);
        skel2h_t<0, 0><<<grid, block, 0, stream>>>(nullptr, nullptr, A, A + HALF,
                                                   nullptr, nullptr, B, nullptr);
        skel2h_t<0, 0><<<grid, block, 0, stream>>>(nullptr, nullptr, B, B + HALF,
                                                   nullptr, nullptr, A, nullptr);
        skel2h_t<0, 0><<<grid, block, 0, stream>>>(nullptr, nullptr, A, A + HALF,
                                                   nullptr, nullptr, B, nullptr);
        // final pass fused with reduction: z<32 companion=target, z>=32 companion=pred
        skel2h_t<0, 1><<<grid, block, 0, stream>>>(nullptr, nullptr, B, B + HALF,
                                                   target, pred, nullptr, partials);
        finalize2<<<1, 64, 0, stream>>>(partials, ntiles, out);
    } else {
        // fallback: z=32 path with 2x16MB f16 buffers, per-chain passes
        unsigned short* b0 = (unsigned short*)ws;
        unsigned short* b1 = (unsigned short*)(ws + IMG16);
        float* partials = (float*)(ws + 2 * IMG16);
        dim3 grid(2, nby, BB);
        skel2h_t<1, 0><<<grid, block, 0, stream>>>(pred, pred, nullptr, nullptr,
                                                   nullptr, nullptr, b0, nullptr);
        skel2h_t<0, 0><<<grid, block, 0, stream>>>(nullptr, nullptr, b0, b0,
                                                   nullptr, nullptr, b1, nullptr);
        skel2h_t<0, 0><<<grid, block, 0, stream>>>(nullptr, nullptr, b1, b1,
                                                   nullptr, nullptr, b0, nullptr);
        skel2h_t<0, 0><<<grid, block, 0, stream>>>(nullptr, nullptr, b0, b0,
                                                   nullptr, nullptr, b1, nullptr);
        skel2h_t<0, 1><<<grid, block, 0, stream>>>(nullptr, nullptr, b1, b1,
                                                   target, target, nullptr, partials);
        skel2h_t<1, 0><<<grid, block, 0, stream>>>(target, target, nullptr, nullptr,
                                                   nullptr, nullptr, b0, nullptr);
        skel2h_t<0, 0><<<grid, block, 0, stream>>>(nullptr, nullptr, b0, b0,
                                                   nullptr, nullptr, b1, nullptr);
        skel2h_t<0, 0><<<grid, block, 0, stream>>>(nullptr, nullptr, b1, b1,
                                                   nullptr, nullptr, b0, nullptr);
        skel2h_t<0, 0><<<grid, block, 0, stream>>>(nullptr, nullptr, b0, b0,
                                                   nullptr, nullptr, b1, nullptr);
        skel2h_t<0, 1><<<grid, block, 0, stream>>>(nullptr, nullptr, b1, b1,
                                                   pred, pred, nullptr,
                                                   partials + (size_t)BB * 16 * 2);
        finalize2<<<1, 64, 0, stream>>>(partials, ntiles, out);
    }
}

// Round 15
// 143.401 us; speedup vs baseline: 1.0910x; 1.0910x over previous
//
#include <hip/hip_runtime.h>
#include <hip/hip_fp16.h>
#include <math.h>

#define HH 512
#define WW 512
#define BB 32
#define CHUNK 32

typedef unsigned u32;

#define NEG_INF2 0xFC00FC00u
#define POS_INF2 0x7C007C00u

// Packed f16 ops via inline asm (ROCm 7.2 headers lack __hmin2/__hmax2).
__device__ __forceinline__ u32 pkmin(u32 a, u32 b) {
    u32 r; asm("v_pk_min_f16 %0, %1, %2" : "=v"(r) : "v"(a), "v"(b)); return r;
}
__device__ __forceinline__ u32 pkmax(u32 a, u32 b) {
    u32 r; asm("v_pk_max_f16 %0, %1, %2" : "=v"(r) : "v"(a), "v"(b)); return r;
}
__device__ __forceinline__ u32 pksub(u32 a, u32 b) {   // a - b, both halves
    u32 r; asm("v_pk_add_f16 %0, %1, %2 neg_lo:[0,1] neg_hi:[0,1]" : "=v"(r) : "v"(a), "v"(b)); return r;
}
__device__ __forceinline__ u32 min3p(u32 a, u32 b, u32 c) { return pkmin(pkmin(a, b), c); }
__device__ __forceinline__ u32 max3p(u32 a, u32 b, u32 c) { return pkmax(pkmax(a, b), c); }

// {lo: a.hi, hi: b.lo} — the shift-by-one-element view between packed pairs.
__device__ __forceinline__ u32 shl1(u32 a, u32 b) {
    return __builtin_amdgcn_alignbit(b, a, 16);
}

union H2U { __half2 h; u32 u; };
__device__ __forceinline__ u32 f2toh2(float lo, float hi) {
    H2U t; t.h = __float22half2_rn(make_float2(lo, hi)); return t.u;
}
__device__ __forceinline__ float2 h2tof2(u32 v) {
    H2U t; t.u = v; return __half22float2(t.h);
}

// Clamped 12-element row load as 6 packed pairs (element e_i = col gx0-4+i).
// Row clamp wave-uniform; col bases pre-clamped. Edge fixups (duplicate an
// in-window value; never changes a min): e3=e0 (lane s==0), e8=e7 (s==127).
template <int F32>
__device__ __forceinline__ void loadrow6(const float* __restrict__ imgF,
                                         const unsigned short* __restrict__ imgH,
                                         int R, int cm4, int c0, int cp4,
                                         bool isL, bool isR, u32* X) {
    const int Rc = R < 0 ? 0 : (R > HH - 1 ? HH - 1 : R);
    if (F32) {
        const float* rb = imgF + (size_t)Rc * WW;
        float4 v0 = *(const float4*)(rb + cm4);
        float4 v1 = *(const float4*)(rb + c0);
        float4 v2 = *(const float4*)(rb + cp4);
        X[0] = f2toh2(v0.x, v0.y); X[1] = f2toh2(v0.z, v0.w);
        X[2] = f2toh2(v1.x, v1.y); X[3] = f2toh2(v1.z, v1.w);
        X[4] = f2toh2(v2.x, v2.y); X[5] = f2toh2(v2.z, v2.w);
    } else {
        const unsigned short* rb = imgH + (size_t)Rc * WW;
        uint2 a = *(const uint2*)(rb + cm4);
        uint2 b = *(const uint2*)(rb + c0);
        uint2 c = *(const uint2*)(rb + cp4);
        X[0] = a.x; X[1] = a.y; X[2] = b.x; X[3] = b.y; X[4] = c.x; X[5] = c.y;
    }
    u32 fl = __builtin_amdgcn_perm(X[0], X[1], 0x05040100u);   // {X1.lo, X0.lo}
    X[1] = isL ? fl : X[1];
    u32 fr = __builtin_amdgcn_perm(X[4], X[3], 0x07060302u);   // {X4.hi, X3.hi}
    X[4] = isR ? fr : X[4];
}

// One row of the T=2 packed-f16 pipeline. Ring roles passed explicitly
// (4-row caller body -> zero cross-iteration copies). Masks mk[8]:
// mn0 {0..3} (pkmin), x1 {4,5} (pkmax), mn1 {6,7} (pkmin).
template <int SRCF32, int FUSED>
__device__ __forceinline__ void rowstep(
    const float* __restrict__ imgF, const unsigned short* __restrict__ imgH,
    const float* __restrict__ cmp, unsigned short* __restrict__ outp,
    float& acc0, float& acc1,
    int R, int cm4, int gx0, int cp4, bool isL, bool isR, bool doStore,
    u32 (&X)[6], u32 (&XL)[6],
    u32 (&hm0o)[6], u32 (&hm0n)[6], u32 (&mn0p)[4],
    u32 (&hx0o)[4], u32 (&hx0n)[4],
    u32 (&x0o)[4], u32 (&x0n)[4],
    u32 (&hm1o)[4], u32 (&hm1n)[4], u32 (&mn1p)[2],
    u32 (&hx1o)[2], u32 (&hx1n)[2],
    u32 (&x1o)[2], u32 (&x1n)[2],
    const u32 (&mk)[8],
    float4& cqC, float4& cqL) {
    loadrow6<SRCF32>(imgF, imgH, R + 3, cm4, gx0, cp4, isL, isR, XL);

    float4 cmpCur;
    if (FUSED) {
        cmpCur = cqC;
        int Rc = R - 1;
        Rc = Rc < 0 ? 0 : (Rc > HH - 1 ? HH - 1 : Rc);
        cqL = *(const float4*)(cmp + (size_t)Rc * WW + gx0);
    }

    // ---- iter1 horizontal min3, row R (pairs 0..5; e0/e11 garbage, unconsumed)
    u32 L[7];
    L[0] = shl1(X[0], X[0]);
    #pragma unroll
    for (int j = 1; j <= 5; ++j) L[j] = shl1(X[j - 1], X[j]);
    L[6] = shl1(X[5], X[5]);
    u32 hm0c[6];
    #pragma unroll
    for (int j = 0; j < 6; ++j) hm0c[j] = min3p(L[j], X[j], L[j + 1]);

    // ---- iter1 min-pool row R-1 (vertical) + masks
    u32 M[6];
    #pragma unroll
    for (int j = 0; j < 6; ++j) M[j] = min3p(hm0o[j], hm0n[j], hm0c[j]);
    if (!((unsigned)(R - 1) < HH)) {            // wave-uniform, rarely taken
        #pragma unroll
        for (int j = 0; j < 6; ++j) M[j] = NEG_INF2;
    }
    M[0] = pkmin(M[0], mk[0]); M[1] = pkmin(M[1], mk[1]);
    M[4] = pkmin(M[4], mk[2]); M[5] = pkmin(M[5], mk[3]);

    // ---- horiz max3 of M, pairs 1..4
    u32 ML[6];
    #pragma unroll
    for (int j = 1; j <= 5; ++j) ML[j] = shl1(M[j - 1], M[j]);
    u32 hx0c[4];
    #pragma unroll
    for (int j = 0; j < 4; ++j) hx0c[j] = max3p(ML[j + 1], M[j + 1], ML[j + 2]);

    // ---- iter1 update: x1 row R-2 (pairs 1..4 -> idx 0..3 = e2..e9)
    u32 x1c[4];
    #pragma unroll
    for (int j = 0; j < 4; ++j) {
        u32 mp = max3p(hx0o[j], hx0n[j], hx0c[j]);
        u32 ct = pkmax(pksub(mp, mn0p[j]), 0u);
        x1c[j] = pkmax(pksub(x0o[j], ct), 0u);
    }
    if (!((unsigned)(R - 2) < HH)) {
        #pragma unroll
        for (int j = 0; j < 4; ++j) x1c[j] = POS_INF2;
    }
    x1c[0] = pkmax(x1c[0], mk[4]);
    x1c[3] = pkmax(x1c[3], mk[5]);

    // rotate iter1 rings (renamed by unrolled caller)
    #pragma unroll
    for (int j = 0; j < 6; ++j) hm0o[j] = hm0c[j];
    #pragma unroll
    for (int j = 0; j < 4; ++j) { mn0p[j] = M[j + 1]; hx0o[j] = hx0c[j]; x0o[j] = X[j + 1]; }

    // ---- iter2 horizontal min3 of x1 (idx 0..3 = e2..e9)
    u32 XL1[5];
    XL1[0] = shl1(x1c[0], x1c[0]);
    #pragma unroll
    for (int j = 1; j <= 3; ++j) XL1[j] = shl1(x1c[j - 1], x1c[j]);
    XL1[4] = shl1(x1c[3], x1c[3]);
    u32 hm1c[4];
    #pragma unroll
    for (int j = 0; j < 4; ++j) hm1c[j] = min3p(XL1[j], x1c[j], XL1[j + 1]);

    // ---- iter2 min-pool row R-3 + masks
    u32 M1[4];
    #pragma unroll
    for (int j = 0; j < 4; ++j) M1[j] = min3p(hm1o[j], hm1n[j], hm1c[j]);
    if (!((unsigned)(R - 3) < HH)) {
        #pragma unroll
        for (int j = 0; j < 4; ++j) M1[j] = NEG_INF2;
    }
    M1[0] = pkmin(M1[0], mk[6]);
    M1[3] = pkmin(M1[3], mk[7]);

    // ---- horiz max3 of M1 at output pairs (idx 1,2 = e4..e7)
    u32 M1s[4];
    #pragma unroll
    for (int j = 1; j <= 3; ++j) M1s[j] = shl1(M1[j - 1], M1[j]);
    u32 hx1c[2];
    hx1c[0] = max3p(M1s[1], M1[1], M1s[2]);
    hx1c[1] = max3p(M1s[2], M1[2], M1s[3]);

    // ---- iter2 update: out row R-4 (wave-uniform branch)
    if (doStore) {
        u32 o[2];
        #pragma unroll
        for (int k = 0; k < 2; ++k) {
            u32 mp = max3p(hx1o[k], hx1n[k], hx1c[k]);
            u32 ct = pkmax(pksub(mp, mn1p[k]), 0u);
            o[k] = pkmax(pksub(x1o[k], ct), 0u);
        }
        if (FUSED) {
            float2 f0 = h2tof2(o[0]);
            float2 f1 = h2tof2(o[1]);
            acc0 += f0.x * cmpCur.x + f0.y * cmpCur.y + f1.x * cmpCur.z + f1.y * cmpCur.w;
            acc1 += f0.x + f0.y + f1.x + f1.y;
        } else {
            uint2 ov;
            ov.x = o[0]; ov.y = o[1];
            *(uint2*)(outp + (size_t)(R - 4) * WW + gx0) = ov;
        }
    }

    // rotate iter2 rings
    #pragma unroll
    for (int j = 0; j < 4; ++j) hm1o[j] = hm1c[j];
    mn1p[0] = M1[1]; mn1p[1] = M1[2];
    hx1o[0] = hx1c[0]; hx1o[1] = hx1c[1];
    x1o[0] = x1c[1]; x1o[1] = x1c[2];
}

// Two fused soft-skeletonize iterations (T=2), packed-f16 via v_pk_min/max
// inline asm, f16 intermediates, no LDS, 4-row rotated loop body
// (I$-resident, zero cross-iteration movs), CHUNK=32 (1.25x warm-up
// overhead, grid 512 blocks = exactly 2/CU — round 8/14 lesson).
template <int SRCF32, int FUSED>
__global__ __launch_bounds__(256) void skel2h_t(const float* __restrict__ sfA,
                                                const float* __restrict__ sfB,
                                                const unsigned short* __restrict__ shA,
                                                const unsigned short* __restrict__ shB,
                                                const float* __restrict__ cmpA,
                                                const float* __restrict__ cmpB,
                                                unsigned short* __restrict__ dst,
                                                float* __restrict__ partials) {
    const int s = blockIdx.x * 64 + threadIdx.x;            // span 0..127
    const int y0 = (blockIdx.y * 4 + threadIdx.y) * CHUNK;  // output row start
    const int z = blockIdx.z;
    const float* imgF = nullptr;
    const unsigned short* imgH = nullptr;
    if (SRCF32) imgF = (z < BB) ? (sfA + (size_t)z * (HH * WW))
                                : (sfB + (size_t)(z - BB) * (HH * WW));
    else        imgH = (z < BB) ? (shA + (size_t)z * (HH * WW))
                                : (shB + (size_t)(z - BB) * (HH * WW));
    const float* cmp = nullptr;
    if (FUSED) cmp = (z < BB) ? (cmpA + (size_t)z * (HH * WW))
                              : (cmpB + (size_t)(z - BB) * (HH * WW));
    unsigned short* outp = FUSED ? nullptr : (dst + (size_t)z * (HH * WW));
    const int gx0 = 4 * s;
    const bool isL = (s == 0), isR = (s == 127);
    const int cm4 = isL ? 0 : gx0 - 4;
    const int cp4 = isR ? gx0 : gx0 + 4;

    // per-lane boundary mask words (lo16 = even element, hi16 = odd)
    u32 mk[8];
    mk[0] = isL ? 0xFC007C00u : POS_INF2;   // mn0 pair0: force e1 -> -inf
    mk[1] = isL ? NEG_INF2    : POS_INF2;   // mn0 pair1: force e2,e3
    mk[2] = isR ? NEG_INF2    : POS_INF2;   // mn0 pair4: force e8,e9
    mk[3] = isR ? 0x7C00FC00u : POS_INF2;   // mn0 pair5: force e10
    mk[4] = isL ? POS_INF2    : NEG_INF2;   // x1 idx0: force e2,e3 -> +inf
    mk[5] = isR ? POS_INF2    : NEG_INF2;   // x1 idx3: force e8,e9
    mk[6] = isL ? 0xFC007C00u : POS_INF2;   // mn1 idx0: force e3
    mk[7] = isR ? 0x7C00FC00u : POS_INF2;   // mn1 idx3: force e8

    // ring state (packed pairs)
    u32 hm0a[6], hm0b[6], mn0p[4];
    u32 hx0a[4], hx0b[4], x0a[4], x0b[4];
    u32 hm1a[4], hm1b[4], mn1p[2];
    u32 hx1a[2], hx1b[2], x1a[2], x1b[2];
    u32 xs0[6], xs1[6], xs2[6], xs3[6];
    float4 cq0, cq1, cq2, cq3;

    #pragma unroll
    for (int j = 0; j < 6; ++j) { hm0a[j] = POS_INF2; hm0b[j] = POS_INF2; }
    #pragma unroll
    for (int j = 0; j < 4; ++j) {
        mn0p[j] = NEG_INF2; hx0a[j] = NEG_INF2; hx0b[j] = NEG_INF2;
        x0a[j] = POS_INF2; x0b[j] = POS_INF2;
        hm1a[j] = POS_INF2; hm1b[j] = POS_INF2;
    }
    #pragma unroll
    for (int k = 0; k < 2; ++k) {
        mn1p[k] = NEG_INF2; hx1a[k] = NEG_INF2; hx1b[k] = NEG_INF2;
        x1a[k] = POS_INF2; x1b[k] = POS_INF2;
    }
    cq0.x = cq0.y = cq0.z = cq0.w = 0.f;
    cq1 = cq0; cq2 = cq0; cq3 = cq0;

    float acc0 = 0.0f, acc1 = 0.0f;

    loadrow6<SRCF32>(imgF, imgH, y0 - 4, cm4, gx0, cp4, isL, isR, xs0);
    loadrow6<SRCF32>(imgF, imgH, y0 - 3, cm4, gx0, cp4, isL, isR, xs1);
    loadrow6<SRCF32>(imgF, imgH, y0 - 2, cm4, gx0, cp4, isL, isR, xs2);

    #pragma unroll 1
    for (int it = 0; it < (CHUNK + 8) / 4; ++it) {
        const int Rb = y0 - 4 + 4 * it;
        const bool doStore = (it >= 2);
        rowstep<SRCF32, FUSED>(imgF, imgH, cmp, outp, acc0, acc1,
            Rb + 0, cm4, gx0, cp4, isL, isR, doStore,
            xs0, xs3, hm0a, hm0b, mn0p, hx0a, hx0b, x0a, x0b,
            hm1a, hm1b, mn1p, hx1a, hx1b, x1a, x1b, mk, cq0, cq3);
        rowstep<SRCF32, FUSED>(imgF, imgH, cmp, outp, acc0, acc1,
            Rb + 1, cm4, gx0, cp4, isL, isR, doStore,
            xs1, xs0, hm0b, hm0a, mn0p, hx0b, hx0a, x0b, x0a,
            hm1b, hm1a, mn1p, hx1b, hx1a, x1b, x1a, mk, cq1, cq0);
        rowstep<SRCF32, FUSED>(imgF, imgH, cmp, outp, acc0, acc1,
            Rb + 2, cm4, gx0, cp4, isL, isR, doStore,
            xs2, xs1, hm0a, hm0b, mn0p, hx0a, hx0b, x0a, x0b,
            hm1a, hm1b, mn1p, hx1a, hx1b, x1a, x1b, mk, cq2, cq1);
        rowstep<SRCF32, FUSED>(imgF, imgH, cmp, outp, acc0, acc1,
            Rb + 3, cm4, gx0, cp4, isL, isR, doStore,
            xs3, xs2, hm0b, hm0a, mn0p, hx0b, hx0a, x0b, x0a,
            hm1b, hm1a, mn1p, hx1b, hx1a, x1b, x1a, mk, cq3, cq2);
    }

    if (FUSED) {
        for (int off = 32; off; off >>= 1) {
            acc0 += __shfl_down(acc0, off);
            acc1 += __shfl_down(acc1, off);
        }
        __shared__ float red[4][2];
        if (threadIdx.x == 0) { red[threadIdx.y][0] = acc0; red[threadIdx.y][1] = acc1; }
        __syncthreads();
        if (threadIdx.x == 0 && threadIdx.y == 0) {
            const int tile = blockIdx.x * gridDim.y + blockIdx.y;  // 0..7
            float* p = partials + ((size_t)z * 16 + tile) * 2;
            p[0] = red[0][0] + red[1][0] + red[2][0] + red[3][0];
            p[1] = red[0][1] + red[1][1] + red[2][1] + red[3][1];
        }
    }
}

// partials layout: [z][16 tile slots][2] (first ntiles used per z);
// z<32: (sum clp*tgt, sum clp); z>=32: (sum skt*prd, sum skt)
__global__ __launch_bounds__(64) void finalize2(const float* __restrict__ partials,
                                                int ntiles,
                                                float* __restrict__ out) {
    const int b = threadIdx.x;
    float iflat = 0.f, tflat = 0.f;
    if (b < BB) {
        float v0 = 0.f, v1 = 0.f, v2 = 0.f, v3 = 0.f;
        for (int t = 0; t < ntiles; ++t) {
            v0 += partials[((size_t)b * 16 + t) * 2 + 0];
            v1 += partials[((size_t)b * 16 + t) * 2 + 1];
            v2 += partials[((size_t)(b + BB) * 16 + t) * 2 + 0];
            v3 += partials[((size_t)(b + BB) * 16 + t) * 2 + 1];
        }
        iflat = (v0 + 1e-6f) / (v1 + 1e-6f);
        tflat = (v2 + 1e-6f) / (v3 + 1e-6f);
    }
    float prod = iflat * tflat;
    float ssum = iflat + tflat;
    for (int off = 32; off; off >>= 1) {
        prod += __shfl_down(prod, off);
        ssum += __shfl_down(ssum, off);
    }
    if (threadIdx.x == 0) out[0] = 1.0f - 2.0f * prod / ssum;
}

extern "C" void kernel_launch(void* const* d_in, const int* in_sizes, int n_in,
                              void* d_out, int out_size, void* d_ws, size_t ws_size,
                              hipStream_t stream) {
    const float* pred = (const float*)d_in[0];
    const float* target = (const float*)d_in[1];
    float* out = (float*)d_out;
    char* ws = (char*)d_ws;
    const size_t N = (size_t)HH * WW;
    const size_t HALF = (size_t)BB * N;                 // elements per 32-image half
    const size_t IMG16 = HALF * sizeof(unsigned short); // 16 MB (f16, 32 imgs)

    dim3 block(64, 4);
    const int nby = HH / (CHUNK * 4);                   // 4
    const int ntiles = 2 * nby;                         // 8

    if (ws_size >= 4 * IMG16 + (1 << 16)) {
        // z=64 path: both chains per dispatch; f16 ping-pong A<->B (32MB each)
        unsigned short* A = (unsigned short*)ws;
        unsigned short* B = (unsigned short*)(ws + 2 * IMG16);
        float* partials = (float*)(ws + 4 * IMG16);     // 64*16*2 floats
        dim3 grid(2, nby, 2 * BB);
        skel2h_t<1, 0><<<grid, block, 0, stream>>>(pred, target, nullptr, nullptr,
                                                   nullptr, nullptr, A, nullptr);
        skel2h_t<0, 0><<<grid, block, 0, stream>>>(nullptr, nullptr, A, A + HALF,
                                                   nullptr, nullptr, B, nullptr);
        skel2h_t<0, 0><<<grid, block, 0, stream>>>(nullptr, nullptr, B, B + HALF,
                                                   nullptr, nullptr, A, nullptr);
        skel2h_t<0, 0><<<grid, block, 0, stream>>>(nullptr, nullptr, A, A + HALF,
                                                   nullptr, nullptr, B, nullptr);
        // final pass fused with reduction: z<32 companion=target, z>=32 companion=pred
        skel2h_t<0, 1><<<grid, block, 0, stream>>>(nullptr, nullptr, B, B + HALF,
                                                   target, pred, nullptr, partials);
        finalize2<<<1, 64, 0, stream>>>(partials, ntiles, out);
    } else {
        // fallback: z=32 path with 2x16MB f16 buffers, per-chain passes
        unsigned short* b0 = (unsigned short*)ws;
        unsigned short* b1 = (unsigned short*)(ws + IMG16);
        float* partials = (float*)(ws + 2 * IMG16);
        dim3 grid(2, nby, BB);
        skel2h_t<1, 0><<<grid, block, 0, stream>>>(pred, pred, nullptr, nullptr,
                                                   nullptr, nullptr, b0, nullptr);
        skel2h_t<0, 0><<<grid, block, 0, stream>>>(nullptr, nullptr, b0, b0,
                                                   nullptr, nullptr, b1, nullptr);
        skel2h_t<0, 0><<<grid, block, 0, stream>>>(nullptr, nullptr, b1, b1,
                                                   nullptr, nullptr, b0, nullptr);
        skel2h_t<0, 0><<<grid, block, 0, stream>>>(nullptr, nullptr, b0, b0,
                                                   nullptr, nullptr, b1, nullptr);
        skel2h_t<0, 1><<<grid, block, 0, stream>>>(nullptr, nullptr, b1, b1,
                                                   target, target, nullptr, partials);
        skel2h_t<1, 0><<<grid, block, 0, stream>>>(target, target, nullptr, nullptr,
                                                   nullptr, nullptr, b0, nullptr);
        skel2h_t<0, 0><<<grid, block, 0, stream>>>(nullptr, nullptr, b0, b0,
                                                   nullptr, nullptr, b1, nullptr);
        skel2h_t<0, 0><<<grid, block, 0, stream>>>(nullptr, nullptr, b1, b1,
                                                   nullptr, nullptr, b0, nullptr);
        skel2h_t<0, 0><<<grid, block, 0, stream>>>(nullptr, nullptr, b0, b0,
                                                   nullptr, nullptr, b1, nullptr);
        skel2h_t<0, 1><<<grid, block, 0, stream>>>(nullptr, nullptr, b1, b1,
                                                   pred, pred, nullptr,
                                                   partials + (size_t)BB * 16 * 2);
        finalize2<<<1, 64, 0, stream>>>(partials, ntiles, out);
    }
}